// Round 7
// baseline (360.390 us; speedup 1.0000x reference)
//
#include <hip/hip_runtime.h>
#include <hip/hip_bf16.h>
#include <cstdint>
#include <cstddef>

#define TT 2048
#define HH 1024
#define FF 2816
#define EE 8
#define BK 64
#define KT1 (HH / BK)   // 16
#define KT2 (FF / BK)   // 44
#define KS 4
#define KTPER (KT2 / KS) // 11
#define NROWS (TT * 2)

typedef short bf16x8 __attribute__((ext_vector_type(8)));
typedef float f32x4v __attribute__((ext_vector_type(4)));
typedef float vf4    __attribute__((ext_vector_type(4)));
typedef unsigned int uint32;

typedef __attribute__((address_space(3))) unsigned int lds_u32;
typedef const __attribute__((address_space(1))) unsigned int glb_u32;

__device__ __forceinline__ void gll16(const void* g, unsigned char* l) {
    __builtin_amdgcn_global_load_lds((glb_u32*)g, (lds_u32*)l, 16, 0, 0);
}

__device__ __forceinline__ unsigned short f2bf(float f) {
    union { float f; uint32 u; } v; v.f = f;
    uint32 u = v.u;
    uint32 r = (u + 0x7FFFu + ((u >> 16) & 1u)) >> 16;  // RNE
    return (unsigned short)r;
}

// prefix-from-counts: seg0 = sum counts[0..e), n_e = counts[e]
__device__ __forceinline__ void seg_of(const int* __restrict__ counts, int e,
                                       int& seg0, int& n_e) {
    int s = 0;
#pragma unroll
    for (int i = 0; i < EE; ++i) s += (i < e) ? counts[i] : 0;
    seg0 = s; n_e = counts[e];
}

// ---------------- router (+ x fp32->bf16 conversion fused) ----------------
__global__ void k_router(const float* __restrict__ x, const float* __restrict__ rw,
                         unsigned short* __restrict__ xb,
                         int* __restrict__ tke, float* __restrict__ tkw,
                         int* __restrict__ counts)
{
    int t = blockIdx.x * 4 + (threadIdx.x >> 6);
    int lane = threadIdx.x & 63;
    const float* xr = x + (size_t)t * HH;
    unsigned short* xbr = xb + (size_t)t * HH;
    float acc[EE];
#pragma unroll
    for (int e = 0; e < EE; ++e) acc[e] = 0.f;
#pragma unroll
    for (int i = 0; i < HH / 64; ++i) {
        int h = i * 64 + lane;
        float xv = xr[h];
        xbr[h] = f2bf(xv);                      // fused convert_x
        const vf4* w = (const vf4*)(rw + (size_t)h * EE);
        vf4 w0 = w[0], w1 = w[1];
#pragma unroll
        for (int e = 0; e < 4; ++e) {
            acc[e]     = fmaf(xv, w0[e], acc[e]);
            acc[4 + e] = fmaf(xv, w1[e], acc[4 + e]);
        }
    }
#pragma unroll
    for (int e = 0; e < EE; ++e) {
        float v = acc[e];
#pragma unroll
        for (int m = 1; m < 64; m <<= 1) v += __shfl_xor(v, m, 64);
        acc[e] = v;
    }
    if (lane == 0) {
        int e1 = 0; float l1 = acc[0];
#pragma unroll
        for (int e = 1; e < EE; ++e) if (acc[e] > l1) { l1 = acc[e]; e1 = e; }
        int e2 = (e1 == 0) ? 1 : 0; float l2 = acc[e2];
#pragma unroll
        for (int e = 0; e < EE; ++e) if (e != e1 && acc[e] > l2) { l2 = acc[e]; e2 = e; }
        float w1 = 1.f / (1.f + __expf(l2 - l1));
        float w2 = 1.f - w1;
        tke[t * 2] = e1; tke[t * 2 + 1] = e2;
        tkw[t * 2] = w1; tkw[t * 2 + 1] = w2;
        atomicAdd(&counts[e1], 1);
        atomicAdd(&counts[e2], 1);
    }
}

// ---------------- weight transpose + convert: [E][K][N] f32 -> [E][N][K] bf16 ------
// z in [0, 2*EE): z<EE -> wg, else wu (fused launch); fixed K=HH, N=FF
__global__ __launch_bounds__(256)
void k_convert_w2(const float* __restrict__ wg, const float* __restrict__ wu,
                  unsigned short* __restrict__ wgT, unsigned short* __restrict__ wuT)
{
    const int z = blockIdx.z;
    const float* src = (z < EE) ? wg : wu;
    unsigned short* dst = (z < EE) ? wgT : wuT;
    const int e = z & (EE - 1);
    const int K = HH, N = FF;
    const int nb = blockIdx.x * 64, kb = blockIdx.y * 64;
    __shared__ unsigned short t_[64][68];
    const int tid = threadIdx.x;
    const float* s = src + ((size_t)e * K + kb) * N + nb;
    {
        int kk = tid >> 4, n4 = (tid & 15) * 4;
#pragma unroll
        for (int i = 0; i < 4; ++i) {
            int k = kk + i * 16;
            vf4 v = *(const vf4*)(s + (size_t)k * N + n4);
#pragma unroll
            for (int j = 0; j < 4; ++j) t_[n4 + j][k] = f2bf(v[j]);
        }
    }
    __syncthreads();
    {
        int n = tid >> 2, c = (tid & 3) * 16;
        unsigned short* d = dst + ((size_t)e * N + nb + n) * K + kb + c;
        uint4 u0 = *(const uint4*)&t_[n][c];
        uint4 u1 = *(const uint4*)&t_[n][c + 8];
        *(uint4*)(d) = u0;
        *(uint4*)(d + 8) = u1;
    }
}

// wd variant: K=FF, N=HH
__global__ __launch_bounds__(256)
void k_convert_wdT(const float* __restrict__ src, unsigned short* __restrict__ dst)
{
    const int e = blockIdx.z;
    const int K = FF, N = HH;
    const int nb = blockIdx.x * 64, kb = blockIdx.y * 64;
    __shared__ unsigned short t_[64][68];
    const int tid = threadIdx.x;
    const float* s = src + ((size_t)e * K + kb) * N + nb;
    {
        int kk = tid >> 4, n4 = (tid & 15) * 4;
#pragma unroll
        for (int i = 0; i < 4; ++i) {
            int k = kk + i * 16;
            vf4 v = *(const vf4*)(s + (size_t)k * N + n4);
#pragma unroll
            for (int j = 0; j < 4; ++j) t_[n4 + j][k] = f2bf(v[j]);
        }
    }
    __syncthreads();
    {
        int n = tid >> 2, c = (tid & 3) * 16;
        unsigned short* d = dst + ((size_t)e * N + nb + n) * K + kb + c;
        uint4 u0 = *(const uint4*)&t_[n][c];
        uint4 u1 = *(const uint4*)&t_[n][c + 8];
        *(uint4*)(d) = u0;
        *(uint4*)(d + 8) = u1;
    }
}

// ---------------- scatter (offsets computed inline from counts) ----------------
__global__ void k_scatter(const int* __restrict__ tke, const float* __restrict__ tkw,
                          const int* __restrict__ counts, int* __restrict__ cursor,
                          int* __restrict__ row_tok, int* __restrict__ row_slot,
                          float* __restrict__ row_w)
{
    int t = blockIdx.x * 256 + threadIdx.x;
    if (t >= TT) return;
    int pre[EE];
    {
        int s = 0;
#pragma unroll
        for (int i = 0; i < EE; ++i) { pre[i] = s; s += counts[i]; }
    }
#pragma unroll
    for (int k = 0; k < 2; ++k) {
        int e = tke[t * 2 + k];
        int pos = atomicAdd(&cursor[e], 1);
        int r = pre[e] + pos;
        row_tok[r] = t;
        row_slot[r] = k;
        row_w[r] = tkw[t * 2 + k];
    }
}

// ---------------- GEMM1: h = silu(x*WgT^t)*(x*WuT^t); BM=128,BN=64 dual ------------
// single-buffer 32KB, m97 2-barrier schedule, 5 blocks/CU
__global__ __launch_bounds__(256, 5)
void k_gemm1(const unsigned short* __restrict__ xb,
             const unsigned short* __restrict__ wgT, const unsigned short* __restrict__ wuT,
             const int* __restrict__ counts, const int* __restrict__ row_tok,
             unsigned short* __restrict__ hb)
{
    const int nbase = blockIdx.x * 64;
    const int e = blockIdx.y >> 4, mt = blockIdx.y & 15;
    int seg0, n_e; seg_of(counts, e, seg0, n_e);
    const int m0 = mt * 128;
    if (m0 >= n_e) return;

    __shared__ __align__(16) unsigned char smem[32768];  // A 16K | Bg 8K | Bu 8K
    const int tid = threadIdx.x, lane = tid & 63, wid = tid >> 6;
    const int wr = wid >> 1, wc = wid & 1;
    const int rl = lane >> 3, cbyte = (lane & 7) * 16;

    // pre-swizzled global sources: LDS slot (row, c) gets global (row, c ^ ((row&7)<<4))
    const char* a_src[4];
#pragma unroll
    for (int i = 0; i < 4; ++i) {
        int r = wid * 32 + i * 8 + rl;
        int gi = m0 + r; int cidx = gi < n_e ? gi : n_e - 1;
        int tok = row_tok[seg0 + cidx];
        a_src[i] = (const char*)xb + (size_t)tok * (HH * 2)
                 + (size_t)(cbyte ^ ((r & 7) << 4));
    }
    const char* bg_src[2]; const char* bu_src[2];
#pragma unroll
    for (int i = 0; i < 2; ++i) {
        int n = wid * 16 + i * 8 + rl;
        size_t rowoff = ((size_t)e * FF + nbase + n) * (HH * 2)
                      + (size_t)(cbyte ^ ((n & 7) << 4));
        bg_src[i] = (const char*)wgT + rowoff;
        bu_src[i] = (const char*)wuT + rowoff;
    }

    auto STAGE = [&](int kt) {
        size_t ko = (size_t)kt * 128;
#pragma unroll
        for (int i = 0; i < 4; ++i) gll16(a_src[i] + ko, smem + wid * 4096 + i * 1024);
#pragma unroll
        for (int i = 0; i < 2; ++i) gll16(bg_src[i] + ko, smem + 16384 + wid * 2048 + i * 1024);
#pragma unroll
        for (int i = 0; i < 2; ++i) gll16(bu_src[i] + ko, smem + 24576 + wid * 2048 + i * 1024);
    };

    f32x4v zero4 = {0.f, 0.f, 0.f, 0.f};
    f32x4v accg[4][2], accu[4][2];
#pragma unroll
    for (int mi = 0; mi < 4; ++mi)
#pragma unroll
        for (int ni = 0; ni < 2; ++ni) { accg[mi][ni] = zero4; accu[mi][ni] = zero4; }

    for (int kt = 0; kt < KT1; ++kt) {
        STAGE(kt);
        __syncthreads();   // drains vmcnt(0): staged data visible
#pragma unroll
        for (int kk = 0; kk < 2; ++kk) {
            const int cb = kk * 64 + ((lane >> 4) << 4);
            bf16x8 af[4], bgf[2], buf_[2];
#pragma unroll
            for (int mi = 0; mi < 4; ++mi) {
                int r = wr * 64 + mi * 16 + (lane & 15);
                af[mi] = *(const bf16x8*)(smem + r * 128 + (cb ^ ((r & 7) << 4)));
            }
#pragma unroll
            for (int ni = 0; ni < 2; ++ni) {
                int n = wc * 32 + ni * 16 + (lane & 15);
                int off = n * 128 + (cb ^ ((n & 7) << 4));
                bgf[ni]  = *(const bf16x8*)(smem + 16384 + off);
                buf_[ni] = *(const bf16x8*)(smem + 24576 + off);
            }
#pragma unroll
            for (int mi = 0; mi < 4; ++mi)
#pragma unroll
                for (int ni = 0; ni < 2; ++ni) {
                    accg[mi][ni] = __builtin_amdgcn_mfma_f32_16x16x32_bf16(af[mi], bgf[ni],  accg[mi][ni], 0, 0, 0);
                    accu[mi][ni] = __builtin_amdgcn_mfma_f32_16x16x32_bf16(af[mi], buf_[ni], accu[mi][ni], 0, 0, 0);
                }
        }
        __syncthreads();   // all reads done before next overwrite
    }

    const int lr = lane >> 4, lc = lane & 15;
#pragma unroll
    for (int mi = 0; mi < 4; ++mi) {
#pragma unroll
        for (int reg = 0; reg < 4; ++reg) {
            int r = wr * 64 + mi * 16 + lr * 4 + reg;
            int gi = m0 + r;
            if (gi < n_e) {
                size_t base = (size_t)(seg0 + gi) * FF;
#pragma unroll
                for (int ni = 0; ni < 2; ++ni) {
                    float g = accg[mi][ni][reg];
                    float u = accu[mi][ni][reg];
                    float hv = g * u / (1.f + __expf(-g));
                    int col = nbase + wc * 32 + ni * 16 + lc;
                    hb[base + col] = f2bf(hv);
                }
            }
        }
    }
}

// ---------------- GEMM2: y = h*WdT^t; BM=128,BN=128, split-K=4 ---------------------
__global__ __launch_bounds__(256, 4)
void k_gemm2(const unsigned short* __restrict__ hb, const unsigned short* __restrict__ wdT,
             const int* __restrict__ counts, const int* __restrict__ row_tok,
             const int* __restrict__ row_slot, const float* __restrict__ row_w,
             float* __restrict__ opart)
{
    const int nbase = blockIdx.x * 128;
    const int e = blockIdx.y >> 4, mt = blockIdx.y & 15;
    const int ks = blockIdx.z;
    int seg0, n_e; seg_of(counts, e, seg0, n_e);
    const int m0 = mt * 128;
    if (m0 >= n_e) return;
    const int kt0 = ks * KTPER;

    __shared__ __align__(16) unsigned char smem[32768];  // A 16K | B 16K
    const int tid = threadIdx.x, lane = tid & 63, wid = tid >> 6;
    const int wr = wid >> 1, wc = wid & 1;
    const int rl = lane >> 3, cbyte = (lane & 7) * 16;

    const char* a_src[4];
#pragma unroll
    for (int i = 0; i < 4; ++i) {
        int r = wid * 32 + i * 8 + rl;
        int gi = m0 + r; int cidx = gi < n_e ? gi : n_e - 1;
        a_src[i] = (const char*)hb + (size_t)(seg0 + cidx) * (FF * 2)
                 + (size_t)(cbyte ^ ((r & 7) << 4));
    }
    const char* b_src[4];
#pragma unroll
    for (int i = 0; i < 4; ++i) {
        int n = wid * 32 + i * 8 + rl;
        b_src[i] = (const char*)wdT + ((size_t)e * HH + nbase + n) * (FF * 2)
                 + (size_t)(cbyte ^ ((n & 7) << 4));
    }

    auto STAGE = [&](int kt) {
        size_t ko = (size_t)kt * 128;
#pragma unroll
        for (int i = 0; i < 4; ++i) gll16(a_src[i] + ko, smem + wid * 4096 + i * 1024);
#pragma unroll
        for (int i = 0; i < 4; ++i) gll16(b_src[i] + ko, smem + 16384 + wid * 4096 + i * 1024);
    };

    f32x4v zero4 = {0.f, 0.f, 0.f, 0.f};
    f32x4v acc[4][4];
#pragma unroll
    for (int mi = 0; mi < 4; ++mi)
#pragma unroll
        for (int ni = 0; ni < 4; ++ni) acc[mi][ni] = zero4;

    for (int it = 0; it < KTPER; ++it) {
        STAGE(kt0 + it);
        __syncthreads();
#pragma unroll
        for (int kk = 0; kk < 2; ++kk) {
            const int cb = kk * 64 + ((lane >> 4) << 4);
            bf16x8 af[4], bf_[4];
#pragma unroll
            for (int mi = 0; mi < 4; ++mi) {
                int r = wr * 64 + mi * 16 + (lane & 15);
                af[mi] = *(const bf16x8*)(smem + r * 128 + (cb ^ ((r & 7) << 4)));
            }
#pragma unroll
            for (int ni = 0; ni < 4; ++ni) {
                int n = wc * 64 + ni * 16 + (lane & 15);
                bf_[ni] = *(const bf16x8*)(smem + 16384 + n * 128 + (cb ^ ((n & 7) << 4)));
            }
#pragma unroll
            for (int mi = 0; mi < 4; ++mi)
#pragma unroll
                for (int ni = 0; ni < 4; ++ni)
                    acc[mi][ni] = __builtin_amdgcn_mfma_f32_16x16x32_bf16(af[mi], bf_[ni], acc[mi][ni], 0, 0, 0);
        }
        __syncthreads();
    }

    const int lr = lane >> 4, lc = lane & 15;
#pragma unroll
    for (int mi = 0; mi < 4; ++mi) {
#pragma unroll
        for (int reg = 0; reg < 4; ++reg) {
            int r = wr * 64 + mi * 16 + lr * 4 + reg;
            int gi = m0 + r;
            if (gi < n_e) {
                int ar  = seg0 + gi;
                int tok = row_tok[ar];
                int sl  = row_slot[ar];
                float wgt = row_w[ar];
                size_t base = ((size_t)(ks * 2 + sl) * TT + tok) * HH;
#pragma unroll
                for (int ni = 0; ni < 4; ++ni) {
                    int col = nbase + wc * 64 + ni * 16 + lc;
                    opart[base + col] = wgt * acc[mi][ni][reg];
                }
            }
        }
    }
}

// ---------------- combine: out = sum of 8 fp32 slices ----------------
__global__ void k_combine(const float* __restrict__ opart, float* __restrict__ out)
{
    int i = (blockIdx.x * 256 + threadIdx.x) * 4;
    vf4 s = {0.f, 0.f, 0.f, 0.f};
#pragma unroll
    for (int k = 0; k < KS * 2; ++k)
        s += *(const vf4*)(opart + (size_t)k * TT * HH + i);
    *(vf4*)(out + i) = s;
}

extern "C" void kernel_launch(void* const* d_in, const int* in_sizes, int n_in,
                              void* d_out, int out_size, void* d_ws, size_t ws_size,
                              hipStream_t stream)
{
    (void)in_sizes; (void)n_in; (void)out_size; (void)ws_size;
    const float* x  = (const float*)d_in[0];
    const float* rw = (const float*)d_in[1];
    const float* wg = (const float*)d_in[2];
    const float* wu = (const float*)d_in[3];
    const float* wd = (const float*)d_in[4];
    float* out = (float*)d_out;

    char* ws = (char*)d_ws;
    size_t off = 0;
    auto alloc = [&](size_t b) { size_t o = off; off += (b + 255) & ~(size_t)255; return o; };
    unsigned short* xb  = (unsigned short*)(ws + alloc((size_t)TT * HH * 2));
    unsigned short* wgT = (unsigned short*)(ws + alloc((size_t)EE * FF * HH * 2));
    unsigned short* wuT = (unsigned short*)(ws + alloc((size_t)EE * FF * HH * 2));
    unsigned short* wdT = (unsigned short*)(ws + alloc((size_t)EE * HH * FF * 2));
    int*   tke      = (int*)  (ws + alloc((size_t)TT * 2 * 4));
    float* tkw      = (float*)(ws + alloc((size_t)TT * 2 * 4));
    int*   cc       = (int*)  (ws + alloc(2 * EE * 4));   // counts | cursor (one memset)
    int*   counts   = cc;
    int*   cursor   = cc + EE;
    int*   row_tok  = (int*)  (ws + alloc((size_t)NROWS * 4));
    int*   row_slot = (int*)  (ws + alloc((size_t)NROWS * 4));
    float* row_w    = (float*)(ws + alloc((size_t)NROWS * 4));
    unsigned short* hb = (unsigned short*)(ws + alloc((size_t)NROWS * FF * 2));
    // opart (8 slices x 8.4 MB = 67 MB) aliases the wgT+wuT region (92 MB),
    // dead after k_gemm1 completes (stream-ordered before k_gemm2).
    float* opart = (float*)wgT;

    hipMemsetAsync(cc, 0, 2 * EE * 4, stream);

    k_router<<<TT / 4, 256, 0, stream>>>(x, rw, xb, tke, tkw, counts);
    {
        dim3 gw(FF / 64, HH / 64, 2 * EE);   // wg+wu fused: K=HH, N=FF
        k_convert_w2<<<gw, 256, 0, stream>>>(wg, wu, wgT, wuT);
        dim3 gd(HH / 64, FF / 64, EE);       // wd: K=FF, N=HH
        k_convert_wdT<<<gd, 256, 0, stream>>>(wd, wdT);
    }
    k_scatter<<<(TT + 255) / 256, 256, 0, stream>>>(tke, tkw, counts, cursor,
                                                    row_tok, row_slot, row_w);
    dim3 g1(FF / 64, 16 * EE);
    k_gemm1<<<g1, 256, 0, stream>>>(xb, wgT, wuT, counts, row_tok, hb);
    dim3 g2(HH / 128, 16 * EE, KS);
    k_gemm2<<<g2, 256, 0, stream>>>(hb, wdT, counts, row_tok, row_slot, row_w, opart);
    k_combine<<<(TT * HH) / (256 * 4), 256, 0, stream>>>(opart, out);
}

// Round 8
// 283.152 us; speedup vs baseline: 1.2728x; 1.2728x over previous
//
#include <hip/hip_runtime.h>
#include <hip/hip_bf16.h>
#include <cstdint>
#include <cstddef>

#define TT 2048
#define HH 1024
#define FF 2816
#define EE 8
#define BK 64
#define KT1 (HH / BK)   // 16
#define KT2 (FF / BK)   // 44
#define KS 4
#define KTPER (KT2 / KS) // 11
#define NROWS (TT * 2)

typedef short bf16x8 __attribute__((ext_vector_type(8)));
typedef float f32x4v __attribute__((ext_vector_type(4)));
typedef float vf4    __attribute__((ext_vector_type(4)));
typedef unsigned int uint32;

typedef __attribute__((address_space(3))) unsigned int lds_u32;
typedef const __attribute__((address_space(1))) unsigned int glb_u32;

__device__ __forceinline__ void gll16(const void* g, unsigned char* l) {
    __builtin_amdgcn_global_load_lds((glb_u32*)g, (lds_u32*)l, 16, 0, 0);
}

__device__ __forceinline__ unsigned short f2bf(float f) {
    union { float f; uint32 u; } v; v.f = f;
    uint32 u = v.u;
    uint32 r = (u + 0x7FFFu + ((u >> 16) & 1u)) >> 16;  // RNE
    return (unsigned short)r;
}

// prefix-from-counts: seg0 = sum counts[0..e), n_e = counts[e]
__device__ __forceinline__ void seg_of(const int* __restrict__ counts, int e,
                                       int& seg0, int& n_e) {
    int s = 0;
#pragma unroll
    for (int i = 0; i < EE; ++i) s += (i < e) ? counts[i] : 0;
    seg0 = s; n_e = counts[e];
}

// ---------------- router (+ x fp32->bf16 conversion fused) ----------------
__global__ void k_router(const float* __restrict__ x, const float* __restrict__ rw,
                         unsigned short* __restrict__ xb,
                         int* __restrict__ tke, float* __restrict__ tkw,
                         int* __restrict__ counts)
{
    int t = blockIdx.x * 4 + (threadIdx.x >> 6);
    int lane = threadIdx.x & 63;
    const float* xr = x + (size_t)t * HH;
    unsigned short* xbr = xb + (size_t)t * HH;
    float acc[EE];
#pragma unroll
    for (int e = 0; e < EE; ++e) acc[e] = 0.f;
#pragma unroll
    for (int i = 0; i < HH / 64; ++i) {
        int h = i * 64 + lane;
        float xv = xr[h];
        xbr[h] = f2bf(xv);                      // fused convert_x
        const vf4* w = (const vf4*)(rw + (size_t)h * EE);
        vf4 w0 = w[0], w1 = w[1];
#pragma unroll
        for (int e = 0; e < 4; ++e) {
            acc[e]     = fmaf(xv, w0[e], acc[e]);
            acc[4 + e] = fmaf(xv, w1[e], acc[4 + e]);
        }
    }
#pragma unroll
    for (int e = 0; e < EE; ++e) {
        float v = acc[e];
#pragma unroll
        for (int m = 1; m < 64; m <<= 1) v += __shfl_xor(v, m, 64);
        acc[e] = v;
    }
    if (lane == 0) {
        int e1 = 0; float l1 = acc[0];
#pragma unroll
        for (int e = 1; e < EE; ++e) if (acc[e] > l1) { l1 = acc[e]; e1 = e; }
        int e2 = (e1 == 0) ? 1 : 0; float l2 = acc[e2];
#pragma unroll
        for (int e = 0; e < EE; ++e) if (e != e1 && acc[e] > l2) { l2 = acc[e]; e2 = e; }
        float w1 = 1.f / (1.f + __expf(l2 - l1));
        float w2 = 1.f - w1;
        tke[t * 2] = e1; tke[t * 2 + 1] = e2;
        tkw[t * 2] = w1; tkw[t * 2 + 1] = w2;
        atomicAdd(&counts[e1], 1);
        atomicAdd(&counts[e2], 1);
    }
}

// ---------------- weight transpose + convert: [E][K][N] f32 -> [E][N][K] bf16 ------
// z in [0, 2*EE): z<EE -> wg, else wu (fused launch); fixed K=HH, N=FF
__global__ __launch_bounds__(256)
void k_convert_w2(const float* __restrict__ wg, const float* __restrict__ wu,
                  unsigned short* __restrict__ wgT, unsigned short* __restrict__ wuT)
{
    const int z = blockIdx.z;
    const float* src = (z < EE) ? wg : wu;
    unsigned short* dst = (z < EE) ? wgT : wuT;
    const int e = z & (EE - 1);
    const int K = HH, N = FF;
    const int nb = blockIdx.x * 64, kb = blockIdx.y * 64;
    __shared__ unsigned short t_[64][68];
    const int tid = threadIdx.x;
    const float* s = src + ((size_t)e * K + kb) * N + nb;
    {
        int kk = tid >> 4, n4 = (tid & 15) * 4;
#pragma unroll
        for (int i = 0; i < 4; ++i) {
            int k = kk + i * 16;
            vf4 v = *(const vf4*)(s + (size_t)k * N + n4);
#pragma unroll
            for (int j = 0; j < 4; ++j) t_[n4 + j][k] = f2bf(v[j]);
        }
    }
    __syncthreads();
    {
        int n = tid >> 2, c = (tid & 3) * 16;
        unsigned short* d = dst + ((size_t)e * N + nb + n) * K + kb + c;
        uint4 u0 = *(const uint4*)&t_[n][c];
        uint4 u1 = *(const uint4*)&t_[n][c + 8];
        *(uint4*)(d) = u0;
        *(uint4*)(d + 8) = u1;
    }
}

// wd variant: K=FF, N=HH
__global__ __launch_bounds__(256)
void k_convert_wdT(const float* __restrict__ src, unsigned short* __restrict__ dst)
{
    const int e = blockIdx.z;
    const int K = FF, N = HH;
    const int nb = blockIdx.x * 64, kb = blockIdx.y * 64;
    __shared__ unsigned short t_[64][68];
    const int tid = threadIdx.x;
    const float* s = src + ((size_t)e * K + kb) * N + nb;
    {
        int kk = tid >> 4, n4 = (tid & 15) * 4;
#pragma unroll
        for (int i = 0; i < 4; ++i) {
            int k = kk + i * 16;
            vf4 v = *(const vf4*)(s + (size_t)k * N + n4);
#pragma unroll
            for (int j = 0; j < 4; ++j) t_[n4 + j][k] = f2bf(v[j]);
        }
    }
    __syncthreads();
    {
        int n = tid >> 2, c = (tid & 3) * 16;
        unsigned short* d = dst + ((size_t)e * N + nb + n) * K + kb + c;
        uint4 u0 = *(const uint4*)&t_[n][c];
        uint4 u1 = *(const uint4*)&t_[n][c + 8];
        *(uint4*)(d) = u0;
        *(uint4*)(d + 8) = u1;
    }
}

// ---------------- scatter (offsets computed inline from counts) ----------------
__global__ void k_scatter(const int* __restrict__ tke, const float* __restrict__ tkw,
                          const int* __restrict__ counts, int* __restrict__ cursor,
                          int* __restrict__ row_tok, int* __restrict__ row_slot,
                          float* __restrict__ row_w)
{
    int t = blockIdx.x * 256 + threadIdx.x;
    if (t >= TT) return;
    int pre[EE];
    {
        int s = 0;
#pragma unroll
        for (int i = 0; i < EE; ++i) { pre[i] = s; s += counts[i]; }
    }
#pragma unroll
    for (int k = 0; k < 2; ++k) {
        int e = tke[t * 2 + k];
        int pos = atomicAdd(&cursor[e], 1);
        int r = pre[e] + pos;
        row_tok[r] = t;
        row_slot[r] = k;
        row_w[r] = tkw[t * 2 + k];
    }
}

// ---------------- GEMM1: h = silu(x*WgT^t)*(x*WuT^t); BM=128,BN=64 dual ------------
// single-buffer 32KB, m97 2-barrier schedule, 4 blocks/CU (5 caused VGPR spills: r7)
__global__ __launch_bounds__(256, 4)
void k_gemm1(const unsigned short* __restrict__ xb,
             const unsigned short* __restrict__ wgT, const unsigned short* __restrict__ wuT,
             const int* __restrict__ counts, const int* __restrict__ row_tok,
             unsigned short* __restrict__ hb)
{
    const int nbase = blockIdx.x * 64;
    const int e = blockIdx.y >> 4, mt = blockIdx.y & 15;
    int seg0, n_e; seg_of(counts, e, seg0, n_e);
    const int m0 = mt * 128;
    if (m0 >= n_e) return;

    __shared__ __align__(16) unsigned char smem[32768];  // A 16K | Bg 8K | Bu 8K
    const int tid = threadIdx.x, lane = tid & 63, wid = tid >> 6;
    const int wr = wid >> 1, wc = wid & 1;
    const int rl = lane >> 3, cbyte = (lane & 7) * 16;

    // pre-swizzled global sources: LDS slot (row, c) gets global (row, c ^ ((row&7)<<4))
    const char* a_src[4];
#pragma unroll
    for (int i = 0; i < 4; ++i) {
        int r = wid * 32 + i * 8 + rl;
        int gi = m0 + r; int cidx = gi < n_e ? gi : n_e - 1;
        int tok = row_tok[seg0 + cidx];
        a_src[i] = (const char*)xb + (size_t)tok * (HH * 2)
                 + (size_t)(cbyte ^ ((r & 7) << 4));
    }
    const char* bg_src[2]; const char* bu_src[2];
#pragma unroll
    for (int i = 0; i < 2; ++i) {
        int n = wid * 16 + i * 8 + rl;
        size_t rowoff = ((size_t)e * FF + nbase + n) * (HH * 2)
                      + (size_t)(cbyte ^ ((n & 7) << 4));
        bg_src[i] = (const char*)wgT + rowoff;
        bu_src[i] = (const char*)wuT + rowoff;
    }

    auto STAGE = [&](int kt) {
        size_t ko = (size_t)kt * 128;
#pragma unroll
        for (int i = 0; i < 4; ++i) gll16(a_src[i] + ko, smem + wid * 4096 + i * 1024);
#pragma unroll
        for (int i = 0; i < 2; ++i) gll16(bg_src[i] + ko, smem + 16384 + wid * 2048 + i * 1024);
#pragma unroll
        for (int i = 0; i < 2; ++i) gll16(bu_src[i] + ko, smem + 24576 + wid * 2048 + i * 1024);
    };

    f32x4v zero4 = {0.f, 0.f, 0.f, 0.f};
    f32x4v accg[4][2], accu[4][2];
#pragma unroll
    for (int mi = 0; mi < 4; ++mi)
#pragma unroll
        for (int ni = 0; ni < 2; ++ni) { accg[mi][ni] = zero4; accu[mi][ni] = zero4; }

    for (int kt = 0; kt < KT1; ++kt) {
        STAGE(kt);
        __syncthreads();   // drains vmcnt(0): staged data visible
#pragma unroll
        for (int kk = 0; kk < 2; ++kk) {
            const int cb = kk * 64 + ((lane >> 4) << 4);
            bf16x8 af[4], bgf[2], buf_[2];
#pragma unroll
            for (int mi = 0; mi < 4; ++mi) {
                int r = wr * 64 + mi * 16 + (lane & 15);
                af[mi] = *(const bf16x8*)(smem + r * 128 + (cb ^ ((r & 7) << 4)));
            }
#pragma unroll
            for (int ni = 0; ni < 2; ++ni) {
                int n = wc * 32 + ni * 16 + (lane & 15);
                int off = n * 128 + (cb ^ ((n & 7) << 4));
                bgf[ni]  = *(const bf16x8*)(smem + 16384 + off);
                buf_[ni] = *(const bf16x8*)(smem + 24576 + off);
            }
#pragma unroll
            for (int mi = 0; mi < 4; ++mi)
#pragma unroll
                for (int ni = 0; ni < 2; ++ni) {
                    accg[mi][ni] = __builtin_amdgcn_mfma_f32_16x16x32_bf16(af[mi], bgf[ni],  accg[mi][ni], 0, 0, 0);
                    accu[mi][ni] = __builtin_amdgcn_mfma_f32_16x16x32_bf16(af[mi], buf_[ni], accu[mi][ni], 0, 0, 0);
                }
        }
        __syncthreads();   // all reads done before next overwrite
    }

    const int lr = lane >> 4, lc = lane & 15;
#pragma unroll
    for (int mi = 0; mi < 4; ++mi) {
#pragma unroll
        for (int reg = 0; reg < 4; ++reg) {
            int r = wr * 64 + mi * 16 + lr * 4 + reg;
            int gi = m0 + r;
            if (gi < n_e) {
                size_t base = (size_t)(seg0 + gi) * FF;
#pragma unroll
                for (int ni = 0; ni < 2; ++ni) {
                    float g = accg[mi][ni][reg];
                    float u = accu[mi][ni][reg];
                    float hv = g * u / (1.f + __expf(-g));
                    int col = nbase + wc * 32 + ni * 16 + lc;
                    hb[base + col] = f2bf(hv);
                }
            }
        }
    }
}

// ---------------- GEMM2: y = h*WdT^t; BM=128,BN=128, split-K=4 ---------------------
__global__ __launch_bounds__(256, 4)
void k_gemm2(const unsigned short* __restrict__ hb, const unsigned short* __restrict__ wdT,
             const int* __restrict__ counts, const int* __restrict__ row_tok,
             const int* __restrict__ row_slot, const float* __restrict__ row_w,
             float* __restrict__ opart)
{
    const int nbase = blockIdx.x * 128;
    const int e = blockIdx.y >> 4, mt = blockIdx.y & 15;
    const int ks = blockIdx.z;
    int seg0, n_e; seg_of(counts, e, seg0, n_e);
    const int m0 = mt * 128;
    if (m0 >= n_e) return;
    const int kt0 = ks * KTPER;

    __shared__ __align__(16) unsigned char smem[32768];  // A 16K | B 16K
    const int tid = threadIdx.x, lane = tid & 63, wid = tid >> 6;
    const int wr = wid >> 1, wc = wid & 1;
    const int rl = lane >> 3, cbyte = (lane & 7) * 16;

    const char* a_src[4];
#pragma unroll
    for (int i = 0; i < 4; ++i) {
        int r = wid * 32 + i * 8 + rl;
        int gi = m0 + r; int cidx = gi < n_e ? gi : n_e - 1;
        a_src[i] = (const char*)hb + (size_t)(seg0 + cidx) * (FF * 2)
                 + (size_t)(cbyte ^ ((r & 7) << 4));
    }
    const char* b_src[4];
#pragma unroll
    for (int i = 0; i < 4; ++i) {
        int n = wid * 32 + i * 8 + rl;
        b_src[i] = (const char*)wdT + ((size_t)e * HH + nbase + n) * (FF * 2)
                 + (size_t)(cbyte ^ ((n & 7) << 4));
    }

    auto STAGE = [&](int kt) {
        size_t ko = (size_t)kt * 128;
#pragma unroll
        for (int i = 0; i < 4; ++i) gll16(a_src[i] + ko, smem + wid * 4096 + i * 1024);
#pragma unroll
        for (int i = 0; i < 4; ++i) gll16(b_src[i] + ko, smem + 16384 + wid * 4096 + i * 1024);
    };

    f32x4v zero4 = {0.f, 0.f, 0.f, 0.f};
    f32x4v acc[4][4];
#pragma unroll
    for (int mi = 0; mi < 4; ++mi)
#pragma unroll
        for (int ni = 0; ni < 4; ++ni) acc[mi][ni] = zero4;

    for (int it = 0; it < KTPER; ++it) {
        STAGE(kt0 + it);
        __syncthreads();
#pragma unroll
        for (int kk = 0; kk < 2; ++kk) {
            const int cb = kk * 64 + ((lane >> 4) << 4);
            bf16x8 af[4], bf_[4];
#pragma unroll
            for (int mi = 0; mi < 4; ++mi) {
                int r = wr * 64 + mi * 16 + (lane & 15);
                af[mi] = *(const bf16x8*)(smem + r * 128 + (cb ^ ((r & 7) << 4)));
            }
#pragma unroll
            for (int ni = 0; ni < 4; ++ni) {
                int n = wc * 64 + ni * 16 + (lane & 15);
                bf_[ni] = *(const bf16x8*)(smem + 16384 + n * 128 + (cb ^ ((n & 7) << 4)));
            }
#pragma unroll
            for (int mi = 0; mi < 4; ++mi)
#pragma unroll
                for (int ni = 0; ni < 4; ++ni)
                    acc[mi][ni] = __builtin_amdgcn_mfma_f32_16x16x32_bf16(af[mi], bf_[ni], acc[mi][ni], 0, 0, 0);
        }
        __syncthreads();
    }

    const int lr = lane >> 4, lc = lane & 15;
#pragma unroll
    for (int mi = 0; mi < 4; ++mi) {
#pragma unroll
        for (int reg = 0; reg < 4; ++reg) {
            int r = wr * 64 + mi * 16 + lr * 4 + reg;
            int gi = m0 + r;
            if (gi < n_e) {
                int ar  = seg0 + gi;
                int tok = row_tok[ar];
                int sl  = row_slot[ar];
                float wgt = row_w[ar];
                size_t base = ((size_t)(ks * 2 + sl) * TT + tok) * HH;
#pragma unroll
                for (int ni = 0; ni < 4; ++ni) {
                    int col = nbase + wc * 64 + ni * 16 + lc;
                    opart[base + col] = wgt * acc[mi][ni][reg];
                }
            }
        }
    }
}

// ---------------- combine: out = sum of 8 fp32 slices ----------------
__global__ void k_combine(const float* __restrict__ opart, float* __restrict__ out)
{
    int i = (blockIdx.x * 256 + threadIdx.x) * 4;
    vf4 s = {0.f, 0.f, 0.f, 0.f};
#pragma unroll
    for (int k = 0; k < KS * 2; ++k)
        s += *(const vf4*)(opart + (size_t)k * TT * HH + i);
    *(vf4*)(out + i) = s;
}

extern "C" void kernel_launch(void* const* d_in, const int* in_sizes, int n_in,
                              void* d_out, int out_size, void* d_ws, size_t ws_size,
                              hipStream_t stream)
{
    (void)in_sizes; (void)n_in; (void)out_size; (void)ws_size;
    const float* x  = (const float*)d_in[0];
    const float* rw = (const float*)d_in[1];
    const float* wg = (const float*)d_in[2];
    const float* wu = (const float*)d_in[3];
    const float* wd = (const float*)d_in[4];
    float* out = (float*)d_out;

    char* ws = (char*)d_ws;
    size_t off = 0;
    auto alloc = [&](size_t b) { size_t o = off; off += (b + 255) & ~(size_t)255; return o; };
    unsigned short* xb  = (unsigned short*)(ws + alloc((size_t)TT * HH * 2));
    unsigned short* wgT = (unsigned short*)(ws + alloc((size_t)EE * FF * HH * 2));
    unsigned short* wuT = (unsigned short*)(ws + alloc((size_t)EE * FF * HH * 2));
    unsigned short* wdT = (unsigned short*)(ws + alloc((size_t)EE * HH * FF * 2));
    int*   tke      = (int*)  (ws + alloc((size_t)TT * 2 * 4));
    float* tkw      = (float*)(ws + alloc((size_t)TT * 2 * 4));
    int*   cc       = (int*)  (ws + alloc(2 * EE * 4));   // counts | cursor (one memset)
    int*   counts   = cc;
    int*   cursor   = cc + EE;
    int*   row_tok  = (int*)  (ws + alloc((size_t)NROWS * 4));
    int*   row_slot = (int*)  (ws + alloc((size_t)NROWS * 4));
    float* row_w    = (float*)(ws + alloc((size_t)NROWS * 4));
    unsigned short* hb = (unsigned short*)(ws + alloc((size_t)NROWS * FF * 2));
    // opart (8 slices x 8.4 MB = 67 MB) aliases the wgT+wuT region (92 MB),
    // dead after k_gemm1 completes (stream-ordered before k_gemm2).
    float* opart = (float*)wgT;

    hipMemsetAsync(cc, 0, 2 * EE * 4, stream);

    k_router<<<TT / 4, 256, 0, stream>>>(x, rw, xb, tke, tkw, counts);
    {
        dim3 gw(FF / 64, HH / 64, 2 * EE);   // wg+wu fused: K=HH, N=FF
        k_convert_w2<<<gw, 256, 0, stream>>>(wg, wu, wgT, wuT);
        dim3 gd(HH / 64, FF / 64, EE);       // wd: K=FF, N=HH
        k_convert_wdT<<<gd, 256, 0, stream>>>(wd, wdT);
    }
    k_scatter<<<(TT + 255) / 256, 256, 0, stream>>>(tke, tkw, counts, cursor,
                                                    row_tok, row_slot, row_w);
    dim3 g1(FF / 64, 16 * EE);
    k_gemm1<<<g1, 256, 0, stream>>>(xb, wgT, wuT, counts, row_tok, hb);
    dim3 g2(HH / 128, 16 * EE, KS);
    k_gemm2<<<g2, 256, 0, stream>>>(hb, wdT, counts, row_tok, row_slot, row_w, opart);
    k_combine<<<(TT * HH) / (256 * 4), 256, 0, stream>>>(opart, out);
}